// Round 1
// baseline (781.357 us; speedup 1.0000x reference)
//
#include <hip/hip_runtime.h>
#include <hip/hip_bf16.h>
#include <math.h>

// Problem constants
#define BB 4
#define CC 64
#define HH 128
#define WW 128
#define OO 64
#define K2 9
#define HW (HH*WW)          // 16384
#define CHW (CC*HW)
#define VAL_STRIDE 580      // 576 + 4 pad -> lane stride 4 banks, <=2-way conflict
#define POS_PER_BLK 16

// ---- Kernel 1: x NCHW -> NHWC ----
__global__ void k_transpose_x(const float* __restrict__ x, float* __restrict__ xt) {
    int idx = blockIdx.x * 256 + threadIdx.x;       // b*H*W*C + y*W*C + xx*C + c
    int c = idx & 63;
    int t = idx >> 6;                               // b*HW + y*W + xx
    int xx = t & 127;
    int y  = (t >> 7) & 127;
    int b  = t >> 14;
    xt[idx] = x[(size_t)b * CHW + (size_t)c * HW + y * WW + xx];
}

// ---- Kernel 2: deform_w [o][c][k] -> wt[(c*9+k)*64 + o] ----
__global__ void k_transpose_w(const float* __restrict__ w, float* __restrict__ wt) {
    int idx = blockIdx.x * 256 + threadIdx.x;       // ck*64 + o
    if (idx >= 576 * 64) return;
    int o  = idx & 63;
    int ck = idx >> 6;
    int c  = ck / 9;
    int k  = ck - c * 9;
    wt[idx] = w[(o * 64 + c) * 9 + k];
}

// ---- Kernel 3: fused offset(18ch) + mask(9ch, sigmoid) 3x3 conv ----
// om layout: [B][27][H][W]; ch 0..17 = offset, 18..26 = mask
__global__ void k_offmask(const float* __restrict__ x,
                          const float* __restrict__ ow, const float* __restrict__ ob,
                          const float* __restrict__ mw, const float* __restrict__ mb,
                          float* __restrict__ om) {
    int gid = blockIdx.x * 256 + threadIdx.x;       // ((b*27+ch)*H + ho)*W + wo
    int wo = gid & 127;
    int ho = (gid >> 7) & 127;
    int bc = gid >> 14;
    int ch = bc % 27;
    int b  = bc / 27;

    const float* w;
    float acc;
    if (ch < 18) { w = ow + ch * 576;        acc = ob[ch]; }
    else         { w = mw + (ch - 18) * 576; acc = mb[ch - 18]; }

    const float* xb = x + (size_t)b * CHW;
    for (int c = 0; c < 64; ++c) {
        const float* xc = xb + c * HW;
        const float* wc = w + c * 9;
        #pragma unroll
        for (int ky = 0; ky < 3; ++ky) {
            int y = ho + ky - 1;
            if ((unsigned)y < (unsigned)HH) {
                const float* row = xc + y * WW;
                #pragma unroll
                for (int kx = 0; kx < 3; ++kx) {
                    int xxc = wo + kx - 1;
                    if ((unsigned)xxc < (unsigned)WW)
                        acc += row[xxc] * wc[ky * 3 + kx];
                }
            }
        }
    }
    if (ch >= 18) acc = 1.0f / (1.0f + expf(-acc));
    om[gid] = acc;
}

// ---- Kernel 4: deformable conv main ----
// Block: 256 threads, 16 consecutive wo positions at fixed (b, ho).
// Phase 1: 144 (pos,k) tasks, lane = c: bilinear sample from NHWC x -> LDS.
// Phase 2: thread = (p = t&15, og = t>>4): 4 output channels, 576-step dot.
__global__ __launch_bounds__(256) void k_deform(const float* __restrict__ xt,
                                                const float* __restrict__ om,
                                                const float* __restrict__ wt,
                                                const float* __restrict__ db,
                                                float* __restrict__ out) {
    __shared__ float val[POS_PER_BLK * VAL_STRIDE];

    int pos0 = blockIdx.x * POS_PER_BLK;
    int wo0 = pos0 & 127;
    int ho  = (pos0 >> 7) & 127;
    int b   = pos0 >> 14;

    int t = threadIdx.x;
    int wave = t >> 6;
    int lane = t & 63;

    const float* omb = om + (size_t)b * 27 * HW;
    const float* xtb = xt + (size_t)b * HW * 64;

    // ---- Phase 1: sampling ----
    #pragma unroll 4
    for (int i = 0; i < 36; ++i) {
        int task = wave * 36 + i;       // 0..143
        int p = task / 9;
        int k = task - p * 9;
        int wo = wo0 + p;
        int sp = ho * WW + wo;
        float dy = omb[(2 * k) * HW + sp];
        float dx = omb[(2 * k + 1) * HW + sp];
        float m  = omb[(18 + k) * HW + sp];
        float py = (float)(ho - 1 + k / 3) + dy;
        float px = (float)(wo - 1 + (k - (k / 3) * 3)) + dx;
        float y0f = floorf(py), x0f = floorf(px);
        float fy = py - y0f, fx = px - x0f;
        int y0 = (int)y0f, x0 = (int)x0f;
        float w00 = (1.0f - fy) * (1.0f - fx);
        float w01 = (1.0f - fy) * fx;
        float w10 = fy * (1.0f - fx);
        float w11 = fy * fx;
        float v = 0.0f;
        if ((unsigned)y0 < (unsigned)HH) {
            const float* row = xtb + (size_t)y0 * (WW * 64);
            if ((unsigned)x0 < (unsigned)WW)        v += w00 * row[x0 * 64 + lane];
            if ((unsigned)(x0 + 1) < (unsigned)WW)  v += w01 * row[(x0 + 1) * 64 + lane];
        }
        if ((unsigned)(y0 + 1) < (unsigned)HH) {
            const float* row = xtb + (size_t)(y0 + 1) * (WW * 64);
            if ((unsigned)x0 < (unsigned)WW)        v += w10 * row[x0 * 64 + lane];
            if ((unsigned)(x0 + 1) < (unsigned)WW)  v += w11 * row[(x0 + 1) * 64 + lane];
        }
        val[p * VAL_STRIDE + lane * 9 + k] = v * m;
    }
    __syncthreads();

    // ---- Phase 2: 64-wide dot over (c,k) per position ----
    int p  = t & 15;
    int og = t >> 4;                    // 0..15, o = og*4 + j
    const float4* wt4 = (const float4*)wt;
    float4 bias = ((const float4*)db)[og];
    float a0 = bias.x, a1 = bias.y, a2 = bias.z, a3 = bias.w;
    const float* vrow = val + p * VAL_STRIDE;
    #pragma unroll 8
    for (int ck = 0; ck < 576; ++ck) {
        float v = vrow[ck];
        float4 w4 = wt4[ck * 16 + og];
        a0 += v * w4.x; a1 += v * w4.y; a2 += v * w4.z; a3 += v * w4.w;
    }
    int o = og * 4;
    float* outp = out + ((size_t)(b * 64 + o) * HH + ho) * WW + wo0 + p;
    outp[0]      = a0;
    outp[HW]     = a1;
    outp[2 * HW] = a2;
    outp[3 * HW] = a3;
}

extern "C" void kernel_launch(void* const* d_in, const int* in_sizes, int n_in,
                              void* d_out, int out_size, void* d_ws, size_t ws_size,
                              hipStream_t stream) {
    const float* x   = (const float*)d_in[0];
    const float* ow  = (const float*)d_in[1];
    const float* ob  = (const float*)d_in[2];
    const float* mw  = (const float*)d_in[3];
    const float* mb  = (const float*)d_in[4];
    const float* dw  = (const float*)d_in[5];
    const float* db  = (const float*)d_in[6];
    float* out = (float*)d_out;

    // workspace layout (floats)
    float* ws   = (float*)d_ws;
    float* xt   = ws;                                   // B*H*W*C     = 4,194,304
    float* om   = xt + (size_t)BB * HW * CC;            // B*27*H*W    = 1,769,472
    float* wt   = om + (size_t)BB * 27 * HW;            // 576*64      =    36,864

    k_transpose_x<<<(BB * HW * CC) / 256, 256, 0, stream>>>(x, xt);
    k_transpose_w<<<(576 * 64 + 255) / 256, 256, 0, stream>>>(dw, wt);
    k_offmask<<<(BB * 27 * HW) / 256, 256, 0, stream>>>(x, ow, ob, mw, mb, om);
    k_deform<<<(BB * HW) / POS_PER_BLK, 256, 0, stream>>>(xt, om, wt, db, out);
}

// Round 2
// 301.656 us; speedup vs baseline: 2.5902x; 2.5902x over previous
//
#include <hip/hip_runtime.h>
#include <hip/hip_bf16.h>
#include <math.h>

// Problem constants
#define BB 4
#define CC 64
#define HH 128
#define WW 128
#define OO 64
#define HW (HH*WW)          // 16384
#define CHW (CC*HW)
#define POS 16              // positions (M) per block
#define AST 584             // A row stride in bf16: 576+8 -> 16B-aligned rows, even bank coverage
#define KSTEPS 18           // 576 / 32

typedef __bf16 bf16;
typedef __attribute__((ext_vector_type(8))) __bf16 bf16x8;
typedef __attribute__((ext_vector_type(4))) float f32x4;

// ---- Kernel 1: x NCHW -> NHWC ----
__global__ void k_transpose_x(const float* __restrict__ x, float* __restrict__ xt) {
    int idx = blockIdx.x * 256 + threadIdx.x;       // b*H*W*C + y*W*C + xx*C + c
    int c = idx & 63;
    int t = idx >> 6;
    int xx = t & 127;
    int y  = (t >> 7) & 127;
    int b  = t >> 14;
    xt[idx] = x[(size_t)b * CHW + (size_t)c * HW + y * WW + xx];
}

// ---- Kernel 2: build B-operand MFMA fragments (hi/lo split) ----
// deform frags: [(ntile*18+ks)*64 + lane]*8 + j, ntile 0..3 (o = ntile*16 + (lane&15))
// offmask frags: same, ntile 0..1 (ch = ntile*16 + (lane&15); ch>=27 -> 0)
__global__ void k_prep_w(const float* __restrict__ dw, const float* __restrict__ ow,
                         const float* __restrict__ mw,
                         bf16* __restrict__ wfd_hi, bf16* __restrict__ wfd_lo,
                         bf16* __restrict__ wfo_hi, bf16* __restrict__ wfo_lo) {
    int idx = blockIdx.x * 256 + threadIdx.x;
    if (idx < 36864) {                              // deform: 4*18*64*8
        int j    = idx & 7;
        int lane = (idx >> 3) & 63;
        int ks   = (idx >> 9) % KSTEPS;
        int nt   = idx / (512 * KSTEPS);
        int n    = nt * 16 + (lane & 15);
        int kglob = ks * 32 + (lane >> 4) * 8 + j;
        int c = kglob / 9, kk = kglob - c * 9;
        float w = dw[(n * 64 + c) * 9 + kk];
        bf16 h = (bf16)w;
        wfd_hi[idx] = h;
        wfd_lo[idx] = (bf16)(w - (float)h);
    } else {                                        // offmask: 2*18*64*8
        int idx2 = idx - 36864;
        if (idx2 < 18432) {
            int j    = idx2 & 7;
            int lane = (idx2 >> 3) & 63;
            int ks   = (idx2 >> 9) % KSTEPS;
            int nt   = idx2 / (512 * KSTEPS);
            int ch   = nt * 16 + (lane & 15);
            int kglob = ks * 32 + (lane >> 4) * 8 + j;
            int c = kglob / 9, kk = kglob - c * 9;
            float w = 0.0f;
            if (ch < 18)      w = ow[(ch * 64 + c) * 9 + kk];
            else if (ch < 27) w = mw[((ch - 18) * 64 + c) * 9 + kk];
            bf16 h = (bf16)w;
            wfo_hi[idx2] = h;
            wfo_lo[idx2] = (bf16)(w - (float)h);
        }
    }
}

// ---- Kernel 3: offset(18) + mask(9, sigmoid) 3x3 conv via split-bf16 MFMA ----
// Block: 16 positions (one row segment). Phase 1: im2col patch -> LDS hi/lo.
// Phase 2: waves 0,1 each do one 16-ch tile: C[16 pos][16 ch] over K=576.
__global__ __launch_bounds__(256) void k_offmask(const float* __restrict__ xt,
        const bf16* __restrict__ wfo_hi, const bf16* __restrict__ wfo_lo,
        const float* __restrict__ ob, const float* __restrict__ mb,
        float* __restrict__ om) {
    __shared__ __align__(16) bf16 a_hi[POS * AST];
    __shared__ __align__(16) bf16 a_lo[POS * AST];

    int pos0 = blockIdx.x * POS;
    int wo0 = pos0 & 127;
    int ho  = (pos0 >> 7) & 127;
    int b   = pos0 >> 14;
    int t = threadIdx.x, wave = t >> 6, lane = t & 63;
    const float* xtb = xt + (size_t)b * CHW;        // NHWC

    #pragma unroll 4
    for (int i = 0; i < 36; ++i) {
        int task = wave * 36 + i;                   // 0..143
        int p = task / 9, kk = task - p * 9;
        int y  = ho + kk / 3 - 1;
        int xx = wo0 + p + (kk % 3) - 1;
        float v = 0.0f;
        if ((unsigned)y < 128u && (unsigned)xx < 128u)
            v = xtb[(y * 128 + xx) * 64 + lane];
        bf16 h = (bf16)v;
        a_hi[p * AST + lane * 9 + kk] = h;
        a_lo[p * AST + lane * 9 + kk] = (bf16)(v - (float)h);
    }
    __syncthreads();

    if (wave < 2) {
        int nt = wave;
        f32x4 acc = {0.f, 0.f, 0.f, 0.f};
        int arow = (lane & 15) * AST + (lane >> 4) * 8;
        const bf16x8* bhp = (const bf16x8*)wfo_hi + (size_t)nt * KSTEPS * 64 + lane;
        const bf16x8* blp = (const bf16x8*)wfo_lo + (size_t)nt * KSTEPS * 64 + lane;
        for (int ks = 0; ks < KSTEPS; ++ks) {
            bf16x8 ah = *(const bf16x8*)&a_hi[arow + ks * 32];
            bf16x8 al = *(const bf16x8*)&a_lo[arow + ks * 32];
            bf16x8 bh = bhp[ks * 64];
            bf16x8 bl = blp[ks * 64];
            acc = __builtin_amdgcn_mfma_f32_16x16x32_bf16(ah, bh, acc, 0, 0, 0);
            acc = __builtin_amdgcn_mfma_f32_16x16x32_bf16(al, bh, acc, 0, 0, 0);
            acc = __builtin_amdgcn_mfma_f32_16x16x32_bf16(ah, bl, acc, 0, 0, 0);
        }
        int ch = nt * 16 + (lane & 15);
        if (ch < 27) {
            float bias = (ch < 18) ? ob[ch] : mb[ch - 18];
            float4 vv;
            float* pv = &vv.x;
            #pragma unroll
            for (int r = 0; r < 4; ++r) {
                float v = acc[r] + bias;
                if (ch >= 18) v = 1.0f / (1.0f + __expf(-v));
                pv[r] = v;
            }
            *(float4*)&om[((size_t)(b * 27 + ch)) * HW + ho * 128 + wo0 + (lane >> 4) * 4] = vv;
        }
    }
}

// ---- Kernel 4: deformable conv via split-bf16 MFMA ----
// Phase 1: 144 (pos,k) wave-tasks, lane=c: bilinear sample * mask -> LDS hi/lo.
// Phase 2: wave = o-tile (0..3): C[16 pos][16 o] over K=576, 3-MFMA split per step.
__global__ __launch_bounds__(256) void k_deform(const float* __restrict__ xt,
        const float* __restrict__ om,
        const bf16* __restrict__ wfd_hi, const bf16* __restrict__ wfd_lo,
        const float* __restrict__ db, float* __restrict__ out) {
    __shared__ __align__(16) bf16 a_hi[POS * AST];
    __shared__ __align__(16) bf16 a_lo[POS * AST];

    int pos0 = blockIdx.x * POS;
    int wo0 = pos0 & 127;
    int ho  = (pos0 >> 7) & 127;
    int b   = pos0 >> 14;
    int t = threadIdx.x, wave = t >> 6, lane = t & 63;
    const float* omb = om + (size_t)b * 27 * HW;
    const float* xtb = xt + (size_t)b * CHW;

    #pragma unroll 4
    for (int i = 0; i < 36; ++i) {
        int task = wave * 36 + i;                   // 0..143
        int p = task / 9, k = task - p * 9;
        int wo = wo0 + p;
        int sp = ho * 128 + wo;
        float dy = omb[(2 * k) * HW + sp];
        float dx = omb[(2 * k + 1) * HW + sp];
        float m  = omb[(18 + k) * HW + sp];
        float py = (float)(ho - 1 + k / 3) + dy;
        float px = (float)(wo - 1 + (k % 3)) + dx;
        float y0f = floorf(py), x0f = floorf(px);
        float fy = py - y0f, fx = px - x0f;
        int y0 = (int)y0f, x0 = (int)x0f;
        float w00 = (1.0f - fy) * (1.0f - fx);
        float w01 = (1.0f - fy) * fx;
        float w10 = fy * (1.0f - fx);
        float w11 = fy * fx;
        float v = 0.0f;
        if ((unsigned)y0 < 128u) {
            const float* row = xtb + (size_t)y0 * (128 * 64);
            if ((unsigned)x0 < 128u)       v += w00 * row[x0 * 64 + lane];
            if ((unsigned)(x0 + 1) < 128u) v += w01 * row[(x0 + 1) * 64 + lane];
        }
        if ((unsigned)(y0 + 1) < 128u) {
            const float* row = xtb + (size_t)(y0 + 1) * (128 * 64);
            if ((unsigned)x0 < 128u)       v += w10 * row[x0 * 64 + lane];
            if ((unsigned)(x0 + 1) < 128u) v += w11 * row[(x0 + 1) * 64 + lane];
        }
        v *= m;
        bf16 h = (bf16)v;
        a_hi[p * AST + lane * 9 + k] = h;
        a_lo[p * AST + lane * 9 + k] = (bf16)(v - (float)h);
    }
    __syncthreads();

    f32x4 acc = {0.f, 0.f, 0.f, 0.f};
    int arow = (lane & 15) * AST + (lane >> 4) * 8;
    const bf16x8* bhp = (const bf16x8*)wfd_hi + (size_t)wave * KSTEPS * 64 + lane;
    const bf16x8* blp = (const bf16x8*)wfd_lo + (size_t)wave * KSTEPS * 64 + lane;
    for (int ks = 0; ks < KSTEPS; ++ks) {
        bf16x8 ah = *(const bf16x8*)&a_hi[arow + ks * 32];
        bf16x8 al = *(const bf16x8*)&a_lo[arow + ks * 32];
        bf16x8 bh = bhp[ks * 64];
        bf16x8 bl = blp[ks * 64];
        acc = __builtin_amdgcn_mfma_f32_16x16x32_bf16(ah, bh, acc, 0, 0, 0);
        acc = __builtin_amdgcn_mfma_f32_16x16x32_bf16(al, bh, acc, 0, 0, 0);
        acc = __builtin_amdgcn_mfma_f32_16x16x32_bf16(ah, bl, acc, 0, 0, 0);
    }
    int o = wave * 16 + (lane & 15);
    float bias = db[o];
    float4 vv = {acc[0] + bias, acc[1] + bias, acc[2] + bias, acc[3] + bias};
    *(float4*)&out[((size_t)(b * 64 + o)) * HW + ho * 128 + wo0 + (lane >> 4) * 4] = vv;
}

extern "C" void kernel_launch(void* const* d_in, const int* in_sizes, int n_in,
                              void* d_out, int out_size, void* d_ws, size_t ws_size,
                              hipStream_t stream) {
    const float* x   = (const float*)d_in[0];
    const float* ow  = (const float*)d_in[1];
    const float* ob  = (const float*)d_in[2];
    const float* mw  = (const float*)d_in[3];
    const float* mb  = (const float*)d_in[4];
    const float* dw  = (const float*)d_in[5];
    const float* db  = (const float*)d_in[6];
    float* out = (float*)d_out;

    float* ws   = (float*)d_ws;
    float* xt   = ws;                               // 4,194,304 f
    float* om   = xt + (size_t)BB * HW * CC;        // 1,769,472 f
    bf16*  wfd_hi = (bf16*)(om + (size_t)BB * 27 * HW);
    bf16*  wfd_lo = wfd_hi + 36864;
    bf16*  wfo_hi = wfd_lo + 36864;
    bf16*  wfo_lo = wfo_hi + 18432;

    k_transpose_x<<<(BB * HW * CC) / 256, 256, 0, stream>>>(x, xt);
    k_prep_w<<<(36864 + 18432) / 256, 256, 0, stream>>>(dw, ow, mw, wfd_hi, wfd_lo, wfo_hi, wfo_lo);
    k_offmask<<<(BB * HW) / POS, 256, 0, stream>>>(xt, wfo_hi, wfo_lo, ob, mb, om);
    k_deform<<<(BB * HW) / POS, 256, 0, stream>>>(xt, om, wfd_hi, wfd_lo, db, out);
}

// Round 3
// 161.636 us; speedup vs baseline: 4.8341x; 1.8663x over previous
//
#include <hip/hip_runtime.h>
#include <hip/hip_bf16.h>
#include <math.h>

// Problem constants
#define BB 4
#define CC 64
#define HH 128
#define WW 128
#define OO 64
#define HW (HH*WW)          // 16384
#define CHW (CC*HW)
#define POS 16              // positions (M rows) per block
#define AST 584             // A row stride in bf16 (576+8, keeps rows 16B aligned)
#define KSTEPS 18           // 576 / 32

typedef __bf16 bf16;
typedef __attribute__((ext_vector_type(8))) __bf16 bf16x8;
typedef __attribute__((ext_vector_type(4))) float f32x4;

// ---- Kernel 1: x NCHW -> NHWC, tiled via LDS ----
__global__ __launch_bounds__(256) void k_transpose_x(const float* __restrict__ x,
                                                     float* __restrict__ xt) {
    __shared__ float tile[64][65];
    int b    = blockIdx.x >> 8;                 // 4 batches
    int s0   = (blockIdx.x & 255) * 64;         // spatial tile start
    int lane = threadIdx.x & 63;
    int w    = threadIdx.x >> 6;                // 0..3
    const float* xb = x + (size_t)b * CHW;
    #pragma unroll
    for (int r = 0; r < 16; ++r) {
        int c = w * 16 + r;
        tile[c][lane] = xb[(size_t)c * HW + s0 + lane];     // coalesced 256B
    }
    __syncthreads();
    float* xtb = xt + (size_t)b * CHW;
    #pragma unroll
    for (int r = 0; r < 16; ++r) {
        int si = w * 16 + r;
        xtb[(size_t)(s0 + si) * 64 + lane] = tile[lane][si]; // coalesced 256B
    }
}

// ---- Kernel 2: build B-operand MFMA fragments (hi + lo weight split) ----
__global__ void k_prep_w(const float* __restrict__ dw, const float* __restrict__ ow,
                         const float* __restrict__ mw,
                         bf16* __restrict__ wfd_hi, bf16* __restrict__ wfd_lo,
                         bf16* __restrict__ wfo_hi, bf16* __restrict__ wfo_lo) {
    int idx = blockIdx.x * 256 + threadIdx.x;
    if (idx < 36864) {                              // deform: 4 tiles * 18 ks * 64 lanes * 8
        int j    = idx & 7;
        int lane = (idx >> 3) & 63;
        int ks   = (idx >> 9) % KSTEPS;
        int nt   = idx / (512 * KSTEPS);
        int n    = nt * 16 + (lane & 15);
        int kglob = ks * 32 + (lane >> 4) * 8 + j;
        int c = kglob / 9, kk = kglob - c * 9;
        float w = dw[(n * 64 + c) * 9 + kk];
        bf16 h = (bf16)w;
        wfd_hi[idx] = h;
        wfd_lo[idx] = (bf16)(w - (float)h);
    } else {                                        // offmask: 2 tiles
        int idx2 = idx - 36864;
        if (idx2 < 18432) {
            int j    = idx2 & 7;
            int lane = (idx2 >> 3) & 63;
            int ks   = (idx2 >> 9) % KSTEPS;
            int nt   = idx2 / (512 * KSTEPS);
            int ch   = nt * 16 + (lane & 15);
            int kglob = ks * 32 + (lane >> 4) * 8 + j;
            int c = kglob / 9, kk = kglob - c * 9;
            float w = 0.0f;
            if (ch < 18)      w = ow[(ch * 64 + c) * 9 + kk];
            else if (ch < 27) w = mw[((ch - 18) * 64 + c) * 9 + kk];
            bf16 h = (bf16)w;
            wfo_hi[idx2] = h;
            wfo_lo[idx2] = (bf16)(w - (float)h);
        }
    }
}

// ---- Kernel 3: fully fused offmask-conv + deformable conv ----
// Phase A : im2col patch (16 pos x 576) -> LDS bf16
// Phase B : 2-wave MFMA -> 27 offset/mask channels -> LDS (sigmoid on mask)
// Phase C1: 144 threads precompute bilinear scalars (weights*m, clamped offsets)
// Phase C2: lane-parallel gather: 4 clamped loads + dot -> LDS bf16 (A reused)
// Phase D : 4-wave MFMA (Ah*Bh + Ah*Bl) -> out
__global__ __launch_bounds__(256) void k_fused(const float* __restrict__ xt,
        const bf16* __restrict__ wfo_hi, const bf16* __restrict__ wfo_lo,
        const bf16* __restrict__ wfd_hi, const bf16* __restrict__ wfd_lo,
        const float* __restrict__ ob, const float* __restrict__ mb,
        const float* __restrict__ db, float* __restrict__ out) {
    __shared__ __align__(16) bf16 a_s[POS * AST];
    __shared__ float om_s[27 * 16];
    __shared__ __align__(16) float sampw[144 * 4];
    __shared__ __align__(16) int   sampo[144 * 4];

    int pos0 = blockIdx.x * POS;
    int wo0 = pos0 & 127;
    int ho  = (pos0 >> 7) & 127;
    int b   = pos0 >> 14;
    int t = threadIdx.x, wave = t >> 6, lane = t & 63;
    const float* xtb = xt + (size_t)b * CHW;

    // ---- Phase A: im2col ----
    #pragma unroll 4
    for (int i = 0; i < 36; ++i) {
        int task = wave * 36 + i;                   // 0..143
        int p = task / 9, kk = task - p * 9;
        int y  = ho + kk / 3 - 1;
        int xx = wo0 + p + (kk % 3) - 1;
        float v = 0.0f;
        if ((unsigned)y < 128u && (unsigned)xx < 128u)
            v = xtb[(y * 128 + xx) * 64 + lane];
        a_s[p * AST + lane * 9 + kk] = (bf16)v;
    }
    __syncthreads();

    // ---- Phase B: offset/mask GEMM on waves 0,1 ----
    if (wave < 2) {
        f32x4 acc = {0.f, 0.f, 0.f, 0.f};
        int arow = (lane & 15) * AST + (lane >> 4) * 8;
        const bf16x8* bhp = (const bf16x8*)wfo_hi + (size_t)wave * KSTEPS * 64 + lane;
        const bf16x8* blp = (const bf16x8*)wfo_lo + (size_t)wave * KSTEPS * 64 + lane;
        for (int ks = 0; ks < KSTEPS; ++ks) {
            bf16x8 ah = *(const bf16x8*)&a_s[arow + ks * 32];
            acc = __builtin_amdgcn_mfma_f32_16x16x32_bf16(ah, bhp[ks * 64], acc, 0, 0, 0);
            acc = __builtin_amdgcn_mfma_f32_16x16x32_bf16(ah, blp[ks * 64], acc, 0, 0, 0);
        }
        int ch = wave * 16 + (lane & 15);
        if (ch < 27) {
            float bias = (ch < 18) ? ob[ch] : mb[ch - 18];
            int pbase = (lane >> 4) * 4;
            #pragma unroll
            for (int r = 0; r < 4; ++r) {
                float v = acc[r] + bias;
                if (ch >= 18) v = 1.0f / (1.0f + __expf(-v));
                om_s[ch * 16 + pbase + r] = v;
            }
        }
    }
    __syncthreads();

    // ---- Phase C1: per-task bilinear scalar precompute ----
    if (t < 144) {
        int p = t / 9, k = t - p * 9;
        float dy = om_s[(2 * k) * 16 + p];
        float dx = om_s[(2 * k + 1) * 16 + p];
        float m  = om_s[(18 + k) * 16 + p];
        float py = (float)(ho - 1 + k / 3) + dy;
        float px = (float)(wo0 + p - 1 + (k % 3)) + dx;
        float y0f = floorf(py), x0f = floorf(px);
        float fy = py - y0f, fx = px - x0f;
        int y0 = (int)y0f, x0 = (int)x0f;
        int y1 = y0 + 1,  x1 = x0 + 1;
        bool vy0 = (unsigned)y0 < 128u, vy1 = (unsigned)y1 < 128u;
        bool vx0 = (unsigned)x0 < 128u, vx1 = (unsigned)x1 < 128u;
        int y0c = min(max(y0, 0), 127), y1c = min(max(y1, 0), 127);
        int x0c = min(max(x0, 0), 127), x1c = min(max(x1, 0), 127);
        sampw[t * 4 + 0] = (vy0 && vx0) ? m * (1.f - fy) * (1.f - fx) : 0.f;
        sampw[t * 4 + 1] = (vy0 && vx1) ? m * (1.f - fy) * fx         : 0.f;
        sampw[t * 4 + 2] = (vy1 && vx0) ? m * fy * (1.f - fx)         : 0.f;
        sampw[t * 4 + 3] = (vy1 && vx1) ? m * fy * fx                 : 0.f;
        sampo[t * 4 + 0] = (y0c * 128 + x0c) * 64;
        sampo[t * 4 + 1] = (y0c * 128 + x1c) * 64;
        sampo[t * 4 + 2] = (y1c * 128 + x0c) * 64;
        sampo[t * 4 + 3] = (y1c * 128 + x1c) * 64;
    }
    __syncthreads();

    // ---- Phase C2: lane-parallel bilinear gather (A buffer reused) ----
    #pragma unroll 4
    for (int i = 0; i < 36; ++i) {
        int task = wave * 36 + i;
        int p = task / 9, k = task - p * 9;
        float4 w4 = *(const float4*)&sampw[task * 4];   // broadcast b128
        int4   o4 = *(const int4*)&sampo[task * 4];     // broadcast b128
        float v = w4.x * xtb[o4.x + lane] + w4.y * xtb[o4.y + lane]
                + w4.z * xtb[o4.z + lane] + w4.w * xtb[o4.w + lane];
        a_s[p * AST + lane * 9 + k] = (bf16)v;
    }
    __syncthreads();

    // ---- Phase D: deform GEMM, all 4 waves ----
    f32x4 acc = {0.f, 0.f, 0.f, 0.f};
    int arow = (lane & 15) * AST + (lane >> 4) * 8;
    const bf16x8* bhp = (const bf16x8*)wfd_hi + (size_t)wave * KSTEPS * 64 + lane;
    const bf16x8* blp = (const bf16x8*)wfd_lo + (size_t)wave * KSTEPS * 64 + lane;
    for (int ks = 0; ks < KSTEPS; ++ks) {
        bf16x8 ah = *(const bf16x8*)&a_s[arow + ks * 32];
        acc = __builtin_amdgcn_mfma_f32_16x16x32_bf16(ah, bhp[ks * 64], acc, 0, 0, 0);
        acc = __builtin_amdgcn_mfma_f32_16x16x32_bf16(ah, blp[ks * 64], acc, 0, 0, 0);
    }
    int o = wave * 16 + (lane & 15);
    float bias = db[o];
    float4 vv = {acc[0] + bias, acc[1] + bias, acc[2] + bias, acc[3] + bias};
    *(float4*)&out[((size_t)(b * 64 + o)) * HW + ho * 128 + wo0 + (lane >> 4) * 4] = vv;
}

extern "C" void kernel_launch(void* const* d_in, const int* in_sizes, int n_in,
                              void* d_out, int out_size, void* d_ws, size_t ws_size,
                              hipStream_t stream) {
    const float* x   = (const float*)d_in[0];
    const float* ow  = (const float*)d_in[1];
    const float* ob  = (const float*)d_in[2];
    const float* mw  = (const float*)d_in[3];
    const float* mb  = (const float*)d_in[4];
    const float* dw  = (const float*)d_in[5];
    const float* db  = (const float*)d_in[6];
    float* out = (float*)d_out;

    float* ws = (float*)d_ws;
    float* xt = ws;                                 // 4,194,304 floats
    bf16*  wfd_hi = (bf16*)(xt + (size_t)BB * HW * CC);
    bf16*  wfd_lo = wfd_hi + 36864;
    bf16*  wfo_hi = wfd_lo + 36864;
    bf16*  wfo_lo = wfo_hi + 18432;

    k_transpose_x<<<BB * 256, 256, 0, stream>>>(x, xt);
    k_prep_w<<<(36864 + 18432) / 256, 256, 0, stream>>>(dw, ow, mw, wfd_hi, wfd_lo, wfo_hi, wfo_lo);
    k_fused<<<(BB * HW) / POS, 256, 0, stream>>>(xt, wfo_hi, wfo_lo, wfd_hi, wfd_lo, ob, mb, db, out);
}

// Round 4
// 142.111 us; speedup vs baseline: 5.4982x; 1.1374x over previous
//
#include <hip/hip_runtime.h>
#include <hip/hip_bf16.h>
#include <math.h>

// Problem constants
#define BB 4
#define CC 64
#define HH 128
#define WW 128
#define OO 64
#define HW (HH*WW)          // 16384
#define CHW (CC*HW)
#define POS 32              // positions (M rows) per block
#define AST 584             // A row stride in bf16 (576+8, keeps rows 16B aligned)
#define KSTEPS 18           // 576 / 32

typedef __bf16 bf16;
typedef __attribute__((ext_vector_type(8))) __bf16 bf16x8;
typedef __attribute__((ext_vector_type(4))) __bf16 bf16x4;
typedef __attribute__((ext_vector_type(4))) float f32x4;

// ---- Pre-kernel: x NCHW -> NHWC transpose (blocks 0..1023) +
//      B-fragment build with K-order k = kk*64 + c (blocks 1024..1239) ----
__global__ __launch_bounds__(256) void k_pre(const float* __restrict__ x,
        float* __restrict__ xt,
        const float* __restrict__ dw, const float* __restrict__ ow,
        const float* __restrict__ mw,
        bf16* __restrict__ wfd_hi, bf16* __restrict__ wfd_lo,
        bf16* __restrict__ wfo_hi, bf16* __restrict__ wfo_lo) {
    __shared__ float tile[64][65];
    if (blockIdx.x < 1024) {
        int b    = blockIdx.x >> 8;
        int s0   = (blockIdx.x & 255) * 64;
        int lane = threadIdx.x & 63;
        int w    = threadIdx.x >> 6;
        const float* xb = x + (size_t)b * CHW;
        #pragma unroll
        for (int r = 0; r < 16; ++r) {
            int c = w * 16 + r;
            tile[c][lane] = xb[(size_t)c * HW + s0 + lane];
        }
        __syncthreads();
        float* xtb = xt + (size_t)b * CHW;
        #pragma unroll
        for (int r = 0; r < 16; ++r) {
            int si = w * 16 + r;
            xtb[(size_t)(s0 + si) * 64 + lane] = tile[lane][si];
        }
    } else {
        int idx = (blockIdx.x - 1024) * 256 + threadIdx.x;
        if (idx < 36864) {                          // deform frags: 4 nt * 18 ks * 64 lanes * 8
            int j    = idx & 7;
            int lane = (idx >> 3) & 63;
            int ks   = (idx >> 9) % KSTEPS;
            int nt   = idx / (512 * KSTEPS);
            int n    = nt * 16 + (lane & 15);
            int kglob = ks * 32 + (lane >> 4) * 8 + j;
            int kk = kglob >> 6, c = kglob & 63;    // K-order: k = kk*64 + c
            float w = dw[(n * 64 + c) * 9 + kk];
            bf16 h = (bf16)w;
            wfd_hi[idx] = h;
            wfd_lo[idx] = (bf16)(w - (float)h);
        } else {
            int idx2 = idx - 36864;                 // offmask frags: 2 nt
            int j    = idx2 & 7;
            int lane = (idx2 >> 3) & 63;
            int ks   = (idx2 >> 9) % KSTEPS;
            int nt   = idx2 / (512 * KSTEPS);
            int ch   = nt * 16 + (lane & 15);
            int kglob = ks * 32 + (lane >> 4) * 8 + j;
            int kk = kglob >> 6, c = kglob & 63;
            float w = 0.0f;
            if (ch < 18)      w = ow[(ch * 64 + c) * 9 + kk];
            else if (ch < 27) w = mw[((ch - 18) * 64 + c) * 9 + kk];
            bf16 h = (bf16)w;
            wfo_hi[idx2] = h;
            wfo_lo[idx2] = (bf16)(w - (float)h);
        }
    }
}

// ---- Fused offmask-conv + deformable conv, 32 positions / block ----
// A : im2col patch (32 x 576) -> LDS bf16, vectorized (task = 16 lanes x float4)
// B : offset/mask GEMM on waves 0,1 (both M-subtiles, B-frags reused) -> om_s
// C1: 288 tasks precompute bilinear scalars (mask-folded weights, clamped offs)
// C2: vectorized bilinear gather -> a_s (reused)
// D : deform GEMM, wave = o-tile, 2 M-subtiles with B-frag register reuse
__global__ __launch_bounds__(256) void k_fused(const float* __restrict__ xt,
        const bf16* __restrict__ wfo_hi, const bf16* __restrict__ wfo_lo,
        const bf16* __restrict__ wfd_hi, const bf16* __restrict__ wfd_lo,
        const float* __restrict__ ob, const float* __restrict__ mb,
        const float* __restrict__ db, float* __restrict__ out) {
    __shared__ __align__(16) bf16 a_s[POS * AST];
    __shared__ float om_s[27 * POS];
    __shared__ __align__(16) float sampw[288 * 4];
    __shared__ __align__(16) int   sampo[288 * 4];

    int pos0 = blockIdx.x * POS;
    int wo0 = pos0 & 127;
    int ho  = (pos0 >> 7) & 127;
    int b   = pos0 >> 14;
    int t = threadIdx.x, wave = t >> 6, lane = t & 63;
    int g = lane >> 4, c4 = (lane & 15) * 4;
    const float* xtb = xt + (size_t)b * CHW;

    // ---- Phase A: im2col, 4 tasks per iteration ----
    #pragma unroll 3
    for (int i = 0; i < 18; ++i) {
        int task = wave * 72 + i * 4 + g;           // 0..287
        int p = task / 9, kk = task - p * 9;
        int y  = ho + kk / 3 - 1;
        int xx = wo0 + p + (kk % 3) - 1;
        float4 v = {0.f, 0.f, 0.f, 0.f};
        if ((unsigned)y < 128u && (unsigned)xx < 128u)
            v = *(const float4*)&xtb[(size_t)(y * 128 + xx) * 64 + c4];
        bf16x4 h = {(bf16)v.x, (bf16)v.y, (bf16)v.z, (bf16)v.w};
        *(bf16x4*)&a_s[p * AST + kk * 64 + c4] = h;
    }
    __syncthreads();

    // ---- Phase B: offset/mask GEMM (waves 0,1; both M-subtiles) ----
    if (wave < 2) {
        int nt = wave;
        f32x4 acc0 = {0.f, 0.f, 0.f, 0.f};
        f32x4 acc1 = {0.f, 0.f, 0.f, 0.f};
        int arow = (lane & 15) * AST + (lane >> 4) * 8;
        const bf16x8* bhp = (const bf16x8*)wfo_hi + (size_t)nt * KSTEPS * 64 + lane;
        const bf16x8* blp = (const bf16x8*)wfo_lo + (size_t)nt * KSTEPS * 64 + lane;
        for (int ks = 0; ks < KSTEPS; ++ks) {
            bf16x8 bh = bhp[ks * 64];
            bf16x8 bl = blp[ks * 64];
            bf16x8 a0 = *(const bf16x8*)&a_s[arow + ks * 32];
            bf16x8 a1 = *(const bf16x8*)&a_s[16 * AST + arow + ks * 32];
            acc0 = __builtin_amdgcn_mfma_f32_16x16x32_bf16(a0, bh, acc0, 0, 0, 0);
            acc0 = __builtin_amdgcn_mfma_f32_16x16x32_bf16(a0, bl, acc0, 0, 0, 0);
            acc1 = __builtin_amdgcn_mfma_f32_16x16x32_bf16(a1, bh, acc1, 0, 0, 0);
            acc1 = __builtin_amdgcn_mfma_f32_16x16x32_bf16(a1, bl, acc1, 0, 0, 0);
        }
        int ch = nt * 16 + (lane & 15);
        if (ch < 27) {
            float bias = (ch < 18) ? ob[ch] : mb[ch - 18];
            int pbase = (lane >> 4) * 4;
            #pragma unroll
            for (int r = 0; r < 4; ++r) {
                float v0 = acc0[r] + bias;
                float v1 = acc1[r] + bias;
                if (ch >= 18) {
                    v0 = 1.0f / (1.0f + __expf(-v0));
                    v1 = 1.0f / (1.0f + __expf(-v1));
                }
                om_s[ch * POS + pbase + r]      = v0;
                om_s[ch * POS + 16 + pbase + r] = v1;
            }
        }
    }
    __syncthreads();

    // ---- Phase C1: per-task bilinear scalar precompute (288 tasks) ----
    for (int task = t; task < 288; task += 256) {
        int p = task / 9, k = task - p * 9;
        float dy = om_s[(2 * k) * POS + p];
        float dx = om_s[(2 * k + 1) * POS + p];
        float m  = om_s[(18 + k) * POS + p];
        float py = (float)(ho - 1 + k / 3) + dy;
        float px = (float)(wo0 + p - 1 + (k % 3)) + dx;
        float y0f = floorf(py), x0f = floorf(px);
        float fy = py - y0f, fx = px - x0f;
        int y0 = (int)y0f, x0 = (int)x0f;
        int y1 = y0 + 1,  x1 = x0 + 1;
        bool vy0 = (unsigned)y0 < 128u, vy1 = (unsigned)y1 < 128u;
        bool vx0 = (unsigned)x0 < 128u, vx1 = (unsigned)x1 < 128u;
        int y0c = min(max(y0, 0), 127), y1c = min(max(y1, 0), 127);
        int x0c = min(max(x0, 0), 127), x1c = min(max(x1, 0), 127);
        sampw[task * 4 + 0] = (vy0 && vx0) ? m * (1.f - fy) * (1.f - fx) : 0.f;
        sampw[task * 4 + 1] = (vy0 && vx1) ? m * (1.f - fy) * fx         : 0.f;
        sampw[task * 4 + 2] = (vy1 && vx0) ? m * fy * (1.f - fx)         : 0.f;
        sampw[task * 4 + 3] = (vy1 && vx1) ? m * fy * fx                 : 0.f;
        sampo[task * 4 + 0] = (y0c * 128 + x0c) * 64;
        sampo[task * 4 + 1] = (y0c * 128 + x1c) * 64;
        sampo[task * 4 + 2] = (y1c * 128 + x0c) * 64;
        sampo[task * 4 + 3] = (y1c * 128 + x1c) * 64;
    }
    __syncthreads();

    // ---- Phase C2: vectorized bilinear gather (a_s reused) ----
    #pragma unroll 3
    for (int i = 0; i < 18; ++i) {
        int task = wave * 72 + i * 4 + g;
        int p = task / 9, k = task - p * 9;
        float4 w4 = *(const float4*)&sampw[task * 4];   // broadcast b128
        int4   o4 = *(const int4*)&sampo[task * 4];     // broadcast b128
        float4 s00 = *(const float4*)&xtb[o4.x + c4];
        float4 s01 = *(const float4*)&xtb[o4.y + c4];
        float4 s10 = *(const float4*)&xtb[o4.z + c4];
        float4 s11 = *(const float4*)&xtb[o4.w + c4];
        float4 v;
        v.x = w4.x * s00.x + w4.y * s01.x + w4.z * s10.x + w4.w * s11.x;
        v.y = w4.x * s00.y + w4.y * s01.y + w4.z * s10.y + w4.w * s11.y;
        v.z = w4.x * s00.z + w4.y * s01.z + w4.z * s10.z + w4.w * s11.z;
        v.w = w4.x * s00.w + w4.y * s01.w + w4.z * s10.w + w4.w * s11.w;
        bf16x4 h = {(bf16)v.x, (bf16)v.y, (bf16)v.z, (bf16)v.w};
        *(bf16x4*)&a_s[p * AST + k * 64 + c4] = h;
    }
    __syncthreads();

    // ---- Phase D: deform GEMM, wave = o-tile, B-frags reused over 2 M-subtiles ----
    f32x4 acc0 = {0.f, 0.f, 0.f, 0.f};
    f32x4 acc1 = {0.f, 0.f, 0.f, 0.f};
    int arow = (lane & 15) * AST + (lane >> 4) * 8;
    const bf16x8* bhp = (const bf16x8*)wfd_hi + (size_t)wave * KSTEPS * 64 + lane;
    const bf16x8* blp = (const bf16x8*)wfd_lo + (size_t)wave * KSTEPS * 64 + lane;
    for (int ks = 0; ks < KSTEPS; ++ks) {
        bf16x8 bh = bhp[ks * 64];
        bf16x8 bl = blp[ks * 64];
        bf16x8 a0 = *(const bf16x8*)&a_s[arow + ks * 32];
        bf16x8 a1 = *(const bf16x8*)&a_s[16 * AST + arow + ks * 32];
        acc0 = __builtin_amdgcn_mfma_f32_16x16x32_bf16(a0, bh, acc0, 0, 0, 0);
        acc0 = __builtin_amdgcn_mfma_f32_16x16x32_bf16(a0, bl, acc0, 0, 0, 0);
        acc1 = __builtin_amdgcn_mfma_f32_16x16x32_bf16(a1, bh, acc1, 0, 0, 0);
        acc1 = __builtin_amdgcn_mfma_f32_16x16x32_bf16(a1, bl, acc1, 0, 0, 0);
    }
    int o = wave * 16 + (lane & 15);
    float bias = db[o];
    float* base = out + ((size_t)(b * 64 + o)) * HW + ho * 128 + wo0 + (lane >> 4) * 4;
    float4 v0 = {acc0[0] + bias, acc0[1] + bias, acc0[2] + bias, acc0[3] + bias};
    float4 v1 = {acc1[0] + bias, acc1[1] + bias, acc1[2] + bias, acc1[3] + bias};
    *(float4*)&base[0]  = v0;
    *(float4*)&base[16] = v1;
}

extern "C" void kernel_launch(void* const* d_in, const int* in_sizes, int n_in,
                              void* d_out, int out_size, void* d_ws, size_t ws_size,
                              hipStream_t stream) {
    const float* x   = (const float*)d_in[0];
    const float* ow  = (const float*)d_in[1];
    const float* ob  = (const float*)d_in[2];
    const float* mw  = (const float*)d_in[3];
    const float* mb  = (const float*)d_in[4];
    const float* dw  = (const float*)d_in[5];
    const float* db  = (const float*)d_in[6];
    float* out = (float*)d_out;

    float* ws = (float*)d_ws;
    float* xt = ws;                                 // 4,194,304 floats
    bf16*  wfd_hi = (bf16*)(xt + (size_t)BB * HW * CC);
    bf16*  wfd_lo = wfd_hi + 36864;
    bf16*  wfo_hi = wfd_lo + 36864;
    bf16*  wfo_lo = wfo_hi + 18432;

    k_pre<<<1024 + 216, 256, 0, stream>>>(x, xt, dw, ow, mw, wfd_hi, wfd_lo, wfo_hi, wfo_lo);
    k_fused<<<(BB * HW) / POS, 256, 0, stream>>>(xt, wfo_hi, wfo_lo, wfd_hi, wfd_lo, ob, mb, db, out);
}

// Round 5
// 127.472 us; speedup vs baseline: 6.1296x; 1.1148x over previous
//
#include <hip/hip_runtime.h>
#include <hip/hip_bf16.h>
#include <math.h>

// Problem constants
#define BB 4
#define CC 64
#define HH 128
#define WW 128
#define HW 16384
#define CHW (CC*HW)

typedef __bf16 bf16;
typedef __attribute__((ext_vector_type(8))) __bf16 bf16x8;
typedef __attribute__((ext_vector_type(4))) __bf16 bf16x4;
typedef __attribute__((ext_vector_type(4))) float f32x4;
typedef __attribute__((ext_vector_type(4))) unsigned short u16x4;

#define MFMA(a, b, c) __builtin_amdgcn_mfma_f32_16x16x32_bf16((a), (b), (c), 0, 0, 0)

// ---- Pre-kernel: x NCHW -> NHWC bf16 (blocks 0..1023) + weight frags ----
__global__ __launch_bounds__(256) void k_pre(const float* __restrict__ x,
        bf16* __restrict__ xt,
        const float* __restrict__ dw, const float* __restrict__ ow,
        const float* __restrict__ mw,
        bf16* __restrict__ wfd_hi, bf16* __restrict__ wfd_lo,
        bf16* __restrict__ wfo_hi, bf16* __restrict__ wfo_lo) {
    __shared__ float tile[64][65];
    if (blockIdx.x < 1024) {
        int b    = blockIdx.x >> 8;
        int s0   = (blockIdx.x & 255) * 64;
        int lane = threadIdx.x & 63;
        int w    = threadIdx.x >> 6;
        const float* xb = x + (size_t)b * CHW;
        #pragma unroll
        for (int r = 0; r < 16; ++r) {
            int c = w * 16 + r;
            tile[c][lane] = xb[(size_t)c * HW + s0 + lane];
        }
        __syncthreads();
        bf16* xtb = xt + (size_t)b * CHW;
        #pragma unroll
        for (int r = 0; r < 16; ++r) {
            int si = w * 16 + r;
            xtb[(size_t)(s0 + si) * 64 + lane] = (bf16)tile[lane][si];
        }
    } else {
        int idx = (blockIdx.x - 1024) * 256 + threadIdx.x;
        if (idx < 36864) {                          // deform frags: 4 nt * 18 ks * 64 lanes * 8
            int j    = idx & 7;
            int lane = (idx >> 3) & 63;
            int ks   = (idx >> 9) % 18;
            int nt   = idx / (512 * 18);
            int n    = nt * 16 + (lane & 15);
            int kglob = ks * 32 + (lane >> 4) * 8 + j;
            int kk = kglob >> 6, c = kglob & 63;    // K-order: k = kk*64 + c
            float w = dw[(n * 64 + c) * 9 + kk];
            bf16 h = (bf16)w;
            wfd_hi[idx] = h;
            wfd_lo[idx] = (bf16)(w - (float)h);
        } else {
            int idx2 = idx - 36864;                 // offmask frags: 2 nt
            int j    = idx2 & 7;
            int lane = (idx2 >> 3) & 63;
            int ks   = (idx2 >> 9) % 18;
            int nt   = idx2 / (512 * 18);
            int ch   = nt * 16 + (lane & 15);
            int kglob = ks * 32 + (lane >> 4) * 8 + j;
            int kk = kglob >> 6, c = kglob & 63;
            float w = 0.0f;
            if (ch < 18)      w = ow[(ch * 64 + c) * 9 + kk];
            else if (ch < 27) w = mw[((ch - 18) * 64 + c) * 9 + kk];
            bf16 h = (bf16)w;
            wfo_hi[idx2] = h;
            wfo_lo[idx2] = (bf16)(w - (float)h);
        }
    }
}

// ---- Fused offmask-conv + deformable conv, 64 positions / block ----
// B : offset/mask GEMM, A-frags direct from global (wave = M-subtile st) -> om_s
// C1: 576 tasks precompute bilinear scalars -> sampw (bf16), sampo (u16)
// per st (4 subtiles of 16 positions):
//   C2: bilinear gather -> a_s in swizzled MFMA-A-frag layout
//   D : deform GEMM (hi-only), wave = o-tile
__global__ __launch_bounds__(256) void k_fused(const bf16* __restrict__ xt,
        const bf16* __restrict__ wfo_hi, const bf16* __restrict__ wfo_lo,
        const bf16* __restrict__ wfd_hi,
        const float* __restrict__ ob, const float* __restrict__ mb,
        const float* __restrict__ db, float* __restrict__ out) {
    __shared__ __align__(16) bf16 a_s[18 * 64 * 8];     // 18432 B, A-frag layout (swizzled)
    __shared__ float om_s[27 * 64];                     // 6912 B
    __shared__ __align__(8) bf16 sampw[576 * 4];        // 4608 B
    __shared__ __align__(8) unsigned short sampo[576 * 4]; // 4608 B

    int pos0 = blockIdx.x * 64;
    int wo0 = pos0 & 127;
    int ho  = (pos0 >> 7) & 127;
    int b   = pos0 >> 14;
    int t = threadIdx.x, wave = t >> 6, lane = t & 63;
    int m = lane & 15, g = lane >> 4;
    const bf16* xtb = xt + (size_t)b * CHW;

    // ---- Phase B: offset/mask GEMM, wave = st, A-frags direct from global ----
    {
        int st = wave;
        f32x4 acc0 = {0.f, 0.f, 0.f, 0.f};
        f32x4 acc1 = {0.f, 0.f, 0.f, 0.f};
        const bf16x8* bh0 = (const bf16x8*)wfo_hi + lane;
        const bf16x8* bl0 = (const bf16x8*)wfo_lo + lane;
        const bf16x8* bh1 = (const bf16x8*)wfo_hi + 18 * 64 + lane;
        const bf16x8* bl1 = (const bf16x8*)wfo_lo + 18 * 64 + lane;
        #pragma unroll
        for (int kk = 0; kk < 9; ++kk) {
            int y  = ho + kk / 3 - 1;
            int xx = wo0 + st * 16 + m + (kk % 3) - 1;
            bf16x8 ae = {};
            bf16x8 ao = {};
            if ((unsigned)y < 128u && (unsigned)xx < 128u) {
                const bf16* bp = xtb + ((size_t)(y * 128 + xx) << 6);
                ae = *(const bf16x8*)(bp + g * 8);
                ao = *(const bf16x8*)(bp + 32 + g * 8);
            }
            int ks0 = 2 * kk, ks1 = 2 * kk + 1;
            acc0 = MFMA(ae, bh0[ks0 * 64], acc0);
            acc0 = MFMA(ae, bl0[ks0 * 64], acc0);
            acc0 = MFMA(ao, bh0[ks1 * 64], acc0);
            acc0 = MFMA(ao, bl0[ks1 * 64], acc0);
            acc1 = MFMA(ae, bh1[ks0 * 64], acc1);
            acc1 = MFMA(ae, bl1[ks0 * 64], acc1);
            acc1 = MFMA(ao, bh1[ks1 * 64], acc1);
            acc1 = MFMA(ao, bl1[ks1 * 64], acc1);
        }
        int p64 = st * 16 + g * 4;
        float bias0 = ob[m];                        // ch = m, always < 18
        #pragma unroll
        for (int r = 0; r < 4; ++r)
            om_s[m * 64 + p64 + r] = acc0[r] + bias0;
        int ch1 = 16 + m;
        if (ch1 < 27) {
            float bias1 = (ch1 < 18) ? ob[ch1] : mb[ch1 - 18];
            #pragma unroll
            for (int r = 0; r < 4; ++r) {
                float v = acc1[r] + bias1;
                if (ch1 >= 18) v = 1.0f / (1.0f + __expf(-v));
                om_s[ch1 * 64 + p64 + r] = v;
            }
        }
    }
    __syncthreads();

    // ---- Phase C1: bilinear scalar precompute (576 tasks) ----
    for (int task = t; task < 576; task += 256) {
        int p64 = task / 9, k = task - p64 * 9;
        float dy = om_s[(2 * k) * 64 + p64];
        float dx = om_s[(2 * k + 1) * 64 + p64];
        float mk = om_s[(18 + k) * 64 + p64];
        float py = (float)(ho - 1 + k / 3) + dy;
        float px = (float)(wo0 + p64 - 1 + (k % 3)) + dx;
        float y0f = floorf(py), x0f = floorf(px);
        float fy = py - y0f, fx = px - x0f;
        int y0 = (int)y0f, x0 = (int)x0f;
        int y1 = y0 + 1,  x1 = x0 + 1;
        bool vy0 = (unsigned)y0 < 128u, vy1 = (unsigned)y1 < 128u;
        bool vx0 = (unsigned)x0 < 128u, vx1 = (unsigned)x1 < 128u;
        int y0c = min(max(y0, 0), 127), y1c = min(max(y1, 0), 127);
        int x0c = min(max(x0, 0), 127), x1c = min(max(x1, 0), 127);
        bf16x4 wv;
        wv.x = (bf16)((vy0 && vx0) ? mk * (1.f - fy) * (1.f - fx) : 0.f);
        wv.y = (bf16)((vy0 && vx1) ? mk * (1.f - fy) * fx         : 0.f);
        wv.z = (bf16)((vy1 && vx0) ? mk * fy * (1.f - fx)         : 0.f);
        wv.w = (bf16)((vy1 && vx1) ? mk * fy * fx                 : 0.f);
        u16x4 ov;
        ov.x = (unsigned short)(y0c * 128 + x0c);
        ov.y = (unsigned short)(y0c * 128 + x1c);
        ov.z = (unsigned short)(y1c * 128 + x0c);
        ov.w = (unsigned short)(y1c * 128 + x1c);
        *(bf16x4*)&sampw[task * 4] = wv;
        *(u16x4*)&sampo[task * 4] = ov;
    }
    __syncthreads();

    // ---- st loop: C2 gather -> a_s, then D GEMM ----
    const bf16x8* bhd = (const bf16x8*)wfd_hi + (size_t)wave * 18 * 64 + lane;
    int c4 = m * 4;
    int p = wave * 4 + g;                           // gather row owned by this 16-lane group
    int gch = (c4 & 31) >> 3;                       // k-chunk within 32
    int kpar = c4 >> 5;                             // ks parity contribution
    int fle = ((m ^ g) + (g << 4)) * 8;             // D-read offsets (elements)
    int flo = ((m ^ g ^ 4) + (g << 4)) * 8;

    for (int st = 0; st < 4; ++st) {
        // C2: each (wave,g) group samples row p, channels c4..c4+3, all 9 kk
        int taskbase = (st * 16 + p) * 9;
        #pragma unroll
        for (int kk = 0; kk < 9; ++kk) {
            int task = taskbase + kk;
            bf16x4 wb = *(const bf16x4*)&sampw[task * 4];
            u16x4  o4 = *(const u16x4*)&sampo[task * 4];
            bf16x4 v00 = *(const bf16x4*)&xtb[((int)o4.x << 6) + c4];
            bf16x4 v01 = *(const bf16x4*)&xtb[((int)o4.y << 6) + c4];
            bf16x4 v10 = *(const bf16x4*)&xtb[((int)o4.z << 6) + c4];
            bf16x4 v11 = *(const bf16x4*)&xtb[((int)o4.w << 6) + c4];
            float w00 = (float)wb.x, w01 = (float)wb.y;
            float w10 = (float)wb.z, w11 = (float)wb.w;
            float r0 = w00 * (float)v00.x + w01 * (float)v01.x + w10 * (float)v10.x + w11 * (float)v11.x;
            float r1 = w00 * (float)v00.y + w01 * (float)v01.y + w10 * (float)v10.y + w11 * (float)v11.y;
            float r2 = w00 * (float)v00.z + w01 * (float)v01.z + w10 * (float)v10.z + w11 * (float)v11.z;
            float r3 = w00 * (float)v00.w + w01 * (float)v01.w + w10 * (float)v10.w + w11 * (float)v11.w;
            int ks = 2 * kk + kpar;
            int fl = (p ^ gch ^ ((ks & 1) << 2)) + (gch << 4);
            bf16x4 hv = {(bf16)r0, (bf16)r1, (bf16)r2, (bf16)r3};
            *(bf16x4*)((char*)a_s + (((ks * 64 + fl) << 4) + ((c4 & 7) << 1))) = hv;
        }
        __syncthreads();

        // D: deform GEMM, wave = o-tile, hi-only
        f32x4 acc = {0.f, 0.f, 0.f, 0.f};
        #pragma unroll
        for (int kk = 0; kk < 9; ++kk) {
            bf16x8 a0 = *(const bf16x8*)&a_s[(2 * kk) * 512 + fle];
            bf16x8 a1 = *(const bf16x8*)&a_s[(2 * kk + 1) * 512 + flo];
            acc = MFMA(a0, bhd[(2 * kk) * 64], acc);
            acc = MFMA(a1, bhd[(2 * kk + 1) * 64], acc);
        }
        int o = wave * 16 + m;
        float bias = db[o];
        float4 vv = {acc[0] + bias, acc[1] + bias, acc[2] + bias, acc[3] + bias};
        *(float4*)&out[((size_t)(b * 64 + o)) * HW + ho * 128 + wo0 + st * 16 + g * 4] = vv;
        if (st < 3) __syncthreads();
    }
}

extern "C" void kernel_launch(void* const* d_in, const int* in_sizes, int n_in,
                              void* d_out, int out_size, void* d_ws, size_t ws_size,
                              hipStream_t stream) {
    const float* x   = (const float*)d_in[0];
    const float* ow  = (const float*)d_in[1];
    const float* ob  = (const float*)d_in[2];
    const float* mw  = (const float*)d_in[3];
    const float* mb  = (const float*)d_in[4];
    const float* dw  = (const float*)d_in[5];
    const float* db  = (const float*)d_in[6];
    float* out = (float*)d_out;

    bf16* xt = (bf16*)d_ws;                         // 4,194,304 bf16 = 8 MB
    bf16* wfd_hi = xt + (size_t)BB * HW * CC;
    bf16* wfd_lo = wfd_hi + 36864;
    bf16* wfo_hi = wfd_lo + 36864;
    bf16* wfo_lo = wfo_hi + 18432;

    k_pre<<<1024 + 216, 256, 0, stream>>>(x, xt, dw, ow, mw, wfd_hi, wfd_lo, wfo_hi, wfo_lo);
    k_fused<<<(BB * HW) / 64, 256, 0, stream>>>(xt, wfo_hi, wfo_lo, wfd_hi, ob, mb, db, out);
}